// Round 9
// baseline (371.962 us; speedup 1.0000x reference)
//
#include <hip/hip_runtime.h>

// ---------- types ----------
typedef __attribute__((ext_vector_type(8))) short bf16x8;   // 8 bf16 = 4 VGPR
typedef __attribute__((ext_vector_type(4))) float f32x4;    // 16x16 MFMA C/D frag
typedef __attribute__((ext_vector_type(16))) float f32x16;  // 32x32 MFMA C/D frag
typedef __attribute__((ext_vector_type(2))) float f32x2;

__device__ __forceinline__ short f2b(float f) {
  union { unsigned u; float f; } c;
  c.f = f;
  unsigned r = (c.u + 0x7FFFu + ((c.u >> 16) & 1u)) >> 16;  // RNE
  return (short)r;
}

// v_cvt_pk_bf16_f32: pack two f32 -> one u32 of 2 bf16 (no builtin on gfx950)
__device__ __forceinline__ int cvt_pk_bf16(float lo, float hi) {
  int r;
  asm("v_cvt_pk_bf16_f32 %0, %1, %2" : "=v"(r) : "v"(lo), "v"(hi));
  return r;
}

// v_permlane32_swap_b32: a' = [a.lo | b.lo], b' = [a.hi | b.hi]
__device__ __forceinline__ void plswap(int& a, int& b) {
  asm("v_permlane32_swap_b32 %0, %1" : "+v"(a), "+v"(b));
}

// v_pk_add_f32: packed 2xf32 add
__device__ __forceinline__ f32x2 pk_add(f32x2 a, f32x2 b) {
  f32x2 d;
  asm("v_pk_add_f32 %0, %1, %2" : "=v"(d) : "v"(a), "v"(b));
  return d;
}

// v_perm_b32 byte shuffle
__device__ __forceinline__ unsigned permb(unsigned s0, unsigned s1, unsigned sel) {
  unsigned d;
  asm("v_perm_b32 %0, %1, %2, %3" : "=v"(d) : "v"(s0), "v"(s1), "s"(sel));
  return d;
}

// async global->LDS, 16B per lane
__device__ __forceinline__ void async16(const void* g, void* l) {
  __builtin_amdgcn_global_load_lds(
      (const __attribute__((address_space(1))) unsigned*)g,
      (__attribute__((address_space(3))) unsigned*)l, 16, 0, 0);
}

// ---------------------------------------------------------------------------
// fp32 -> bf16 conversion, all five tensors in ONE launch.
// ---------------------------------------------------------------------------
__global__ __launch_bounds__(256)
void conv_all(const float* __restrict__ x,  const float* __restrict__ wq,
              const float* __restrict__ wk, const float* __restrict__ wv,
              const float* __restrict__ wo, short* __restrict__ dst) {
  const size_t M = 1048576;
  size_t i = ((size_t)blockIdx.x * 256 + threadIdx.x) * 4;
  const float* src; size_t off;
  if (i < 8 * M)       { src = x;  off = 0; }
  else if (i < 12 * M) { src = wq; off = 8 * M; }
  else if (i < 13 * M) { src = wk; off = 12 * M; }
  else if (i < 14 * M) { src = wv; off = 13 * M; }
  else                 { src = wo; off = 14 * M; }
  float4 v = *(const float4*)(src + (i - off));
  short4 o;
  o.x = f2b(v.x); o.y = f2b(v.y); o.z = f2b(v.z); o.w = f2b(v.w);
  *(short4*)(dst + i) = o;
}

// ---------------------------------------------------------------------------
// 128x128 GEMM, BK=64, 32x32x16 MFMA (round-7 verified). XOR chunk-swizzled
// LDS; XCD-chunked block remap. C/D map: col=l31, row=(r&3)+8(r>>2)+4*hl.
// ---------------------------------------------------------------------------
template <bool F32OUT>
__global__ __launch_bounds__(256)
void gemm_bt_bias(const short* __restrict__ A, const short* __restrict__ Bw,
                  const float* __restrict__ bias, void* __restrict__ Cv,
                  int M, int N, int K) {
  __shared__ short lsA[128 * 64];
  __shared__ short lsB[128 * 64];
  const int tid  = threadIdx.x;
  const int wave = tid >> 6, lane = tid & 63;
  const int l31  = lane & 31, hl = lane >> 5;
  const int GX  = gridDim.x;
  const int nwg = GX * gridDim.y;
  const int dd  = blockIdx.x + blockIdx.y * GX;
  const int logical = (dd & 7) * (nwg >> 3) + (dd >> 3);
  const int m0 = (logical / GX) * 128, n0 = (logical % GX) * 128;
  const int wm = (wave >> 1) * 64, wn = (wave & 1) * 64;

  f32x16 acc[2][2];
#pragma unroll
  for (int i = 0; i < 2; i++)
#pragma unroll
    for (int j = 0; j < 2; j++)
#pragma unroll
      for (int r = 0; r < 16; r++) acc[i][j][r] = 0.f;

  const int R  = tid >> 3;               // 0..31
  const int cs = tid & 7;                // chunk 0..7
  const int gc = (cs ^ (R & 7)) << 3;    // pre-swizzled source column
  const short* Arow[4]; const short* Brow[4];
#pragma unroll
  for (int b = 0; b < 4; b++) {
    Arow[b] = A  + (size_t)(m0 + R + 32 * b) * K + gc;
    Brow[b] = Bw + (size_t)(n0 + R + 32 * b) * K + gc;
  }
  const int ldst = R * 64 + cs * 8;

  for (int k0 = 0; k0 < K; k0 += 64) {
#pragma unroll
    for (int b = 0; b < 4; b++) {
      async16(Arow[b] + k0, lsA + ldst + b * 32 * 64);
      async16(Brow[b] + k0, lsB + ldst + b * 32 * 64);
    }
    __syncthreads();

    bf16x8 af[2][4], bfr[2][4];
#pragma unroll
    for (int i = 0; i < 2; i++) {
      const int Rr = wm + i * 32 + l31;
#pragma unroll
      for (int kq = 0; kq < 4; kq++) {
        const int c = kq * 2 + hl;
        af[i][kq] = *(const bf16x8*)(lsA + Rr * 64 + ((c ^ (Rr & 7)) << 3));
      }
    }
#pragma unroll
    for (int j = 0; j < 2; j++) {
      const int Sr = wn + j * 32 + l31;
#pragma unroll
      for (int kq = 0; kq < 4; kq++) {
        const int c = kq * 2 + hl;
        bfr[j][kq] = *(const bf16x8*)(lsB + Sr * 64 + ((c ^ (Sr & 7)) << 3));
      }
    }
#pragma unroll
    for (int kq = 0; kq < 4; kq++)
#pragma unroll
      for (int i = 0; i < 2; i++)
#pragma unroll
        for (int j = 0; j < 2; j++)
          acc[i][j] = __builtin_amdgcn_mfma_f32_32x32x16_bf16(
              af[i][kq], bfr[j][kq], acc[i][j], 0, 0, 0);
    __syncthreads();
  }

#pragma unroll
  for (int j = 0; j < 2; j++) {
    const int col = n0 + wn + j * 32 + l31;
    const float bb = bias[col];
#pragma unroll
    for (int i = 0; i < 2; i++) {
      const int rowb = m0 + wm + i * 32;
#pragma unroll
      for (int r = 0; r < 16; r++) {
        const int row = rowb + (r & 3) + 8 * (r >> 2) + 4 * hl;
        const float val = acc[i][j][r] + bb;
        if (F32OUT)
          ((float*)Cv)[(size_t)row * N + col] = val;
        else
          ((short*)Cv)[(size_t)row * N + col] = f2b(val);
      }
    }
  }
}

// ---------------------------------------------------------------------------
// Fused QKV GEMM, same 32x32x16 structure. Q pre-scaled by 0.125*log2(e).
// ---------------------------------------------------------------------------
__global__ __launch_bounds__(256)
void gemm_qkv(const short* __restrict__ A, const short* __restrict__ Bw,
              const float* __restrict__ bq, const float* __restrict__ bk,
              const float* __restrict__ bv,
              short* __restrict__ Qo, short* __restrict__ Ko, short* __restrict__ Vo) {
  const int K = 2048;
  __shared__ short lsA[128 * 64];
  __shared__ short lsB[128 * 64];
  const int tid  = threadIdx.x;
  const int wave = tid >> 6, lane = tid & 63;
  const int l31  = lane & 31, hl = lane >> 5;
  const int GX  = gridDim.x;
  const int nwg = GX * gridDim.y;
  const int dd  = blockIdx.x + blockIdx.y * GX;
  const int logical = (dd & 7) * (nwg >> 3) + (dd >> 3);
  const int m0 = (logical / GX) * 128, n0 = (logical % GX) * 128;
  const int wm = (wave >> 1) * 64, wn = (wave & 1) * 64;

  f32x16 acc[2][2];
#pragma unroll
  for (int i = 0; i < 2; i++)
#pragma unroll
    for (int j = 0; j < 2; j++)
#pragma unroll
      for (int r = 0; r < 16; r++) acc[i][j][r] = 0.f;

  const int R  = tid >> 3;
  const int cs = tid & 7;
  const int gc = (cs ^ (R & 7)) << 3;
  const short* Arow[4]; const short* Brow[4];
#pragma unroll
  for (int b = 0; b < 4; b++) {
    Arow[b] = A  + (size_t)(m0 + R + 32 * b) * K + gc;
    Brow[b] = Bw + (size_t)(n0 + R + 32 * b) * K + gc;
  }
  const int ldst = R * 64 + cs * 8;

  for (int k0 = 0; k0 < K; k0 += 64) {
#pragma unroll
    for (int b = 0; b < 4; b++) {
      async16(Arow[b] + k0, lsA + ldst + b * 32 * 64);
      async16(Brow[b] + k0, lsB + ldst + b * 32 * 64);
    }
    __syncthreads();

    bf16x8 af[2][4], bfr[2][4];
#pragma unroll
    for (int i = 0; i < 2; i++) {
      const int Rr = wm + i * 32 + l31;
#pragma unroll
      for (int kq = 0; kq < 4; kq++) {
        const int c = kq * 2 + hl;
        af[i][kq] = *(const bf16x8*)(lsA + Rr * 64 + ((c ^ (Rr & 7)) << 3));
      }
    }
#pragma unroll
    for (int j = 0; j < 2; j++) {
      const int Sr = wn + j * 32 + l31;
#pragma unroll
      for (int kq = 0; kq < 4; kq++) {
        const int c = kq * 2 + hl;
        bfr[j][kq] = *(const bf16x8*)(lsB + Sr * 64 + ((c ^ (Sr & 7)) << 3));
      }
    }
#pragma unroll
    for (int kq = 0; kq < 4; kq++)
#pragma unroll
      for (int i = 0; i < 2; i++)
#pragma unroll
        for (int j = 0; j < 2; j++)
          acc[i][j] = __builtin_amdgcn_mfma_f32_32x32x16_bf16(
              af[i][kq], bfr[j][kq], acc[i][j], 0, 0, 0);
    __syncthreads();
  }

  short* base; int stride, coff; const float* bias;
  if (n0 < 2048)      { base = Qo; stride = 2048; bias = bq; coff = 0; }
  else if (n0 < 2560) { base = Ko; stride = 512;  bias = bk; coff = 2048; }
  else                { base = Vo; stride = 512;  bias = bv; coff = 2560; }
  const float qs = (n0 < 2048) ? 0.18033688011112043f : 1.0f;  // 0.125*log2(e)

#pragma unroll
  for (int j = 0; j < 2; j++) {
    const int lc = n0 + wn + j * 32 + l31 - coff;
    const float bb = bias[lc];
#pragma unroll
    for (int i = 0; i < 2; i++) {
      const int rowb = m0 + wm + i * 32;
#pragma unroll
      for (int r = 0; r < 16; r++) {
        const int row = rowb + (r & 3) + 8 * (r >> 2) + 4 * hl;
        base[(size_t)row * stride + lc] = f2b((acc[i][j][r] + bb) * qs);
      }
    }
  }
}

// ---------------------------------------------------------------------------
// Flash GQA v8: v5 compute core (verified) with K taken OUT of LDS.
// QK's A-fragment (lane l = K[l31][f*16+hl*8]) is loaded straight from
// global (L2-resident: 256KB K stream shared by 64 co-XCD blocks), issued
// one tile ahead right after QK consumes the previous frags. Removes per
// tile: 2 K-commits + 8 ds_read_b128 + lgkmcnt waits from the serial chain.
// V keeps the LDS transpose (v_perm pack). LDS 9.7 KiB. 2 barriers/tile.
// ---------------------------------------------------------------------------
#define S_LEN 2048
#define HID   2048
#define KVD   512
#define ST    72

__global__ __launch_bounds__(256)
void gqa_flash(const short* __restrict__ Q, const short* __restrict__ Kb,
               const short* __restrict__ Vb, short* __restrict__ O) {
  __shared__ __align__(16) short lsVt[64 * ST];   // [d][key]
  __shared__ float lsum[4][32];

  const int tid  = threadIdx.x;
  const int wave = tid >> 6, lane = tid & 63;
  const int l31  = lane & 31, hl = lane >> 5;

  const int d  = blockIdx.x + (blockIdx.y << 6);
  const int by = ((d & 7) << 1) | (d >> 9);
  const int qb = (d >> 3) & 63;
  const int b = by >> 3, kvh = by & 7;
  const int h = kvh * 4 + wave;
  const int q0 = qb * 32;

  const short* Qrow = Q + (size_t)(b * S_LEN + q0 + l31) * HID + h * 64 + hl * 8;
  bf16x8 qf[4];
#pragma unroll
  for (int f = 0; f < 4; f++) qf[f] = *(const bf16x8*)(Qrow + f * 16);

  f32x16 o0, o1;
#pragma unroll
  for (int i = 0; i < 16; i++) { o0[i] = 0.f; o1[i] = 0.f; }
  float lloc = 0.f;

  const short* Kp = Kb + (size_t)b * S_LEN * KVD + kvh * 64;
  const short* Vp = Vb + (size_t)b * S_LEN * KVD + kvh * 64;

  // per-wave K fragment pointer: rows l31 / 32+l31, cols f*16 + hl*8
  const short* Kfp = Kp + (size_t)l31 * KVD + hl * 8;
  const int kpV = tid & 31, dcV = (tid >> 5) * 8;

  bf16x8 kr[2][4];               // K frags for the CURRENT tile (32 VGPR)
  auto kload = [&](int kt) {
    const int kn = (kt * 64) & (S_LEN - 1);
    const short* base = Kfp + (size_t)kn * KVD;
#pragma unroll
    for (int half = 0; half < 2; half++)
#pragma unroll
      for (int f = 0; f < 4; f++)
        kr[half][f] = *(const bf16x8*)(base + half * 32 * KVD + f * 16);
  };

  bf16x8 vf0, vf1;
  auto vprefetch = [&](int kt) {
    const int kn = (kt * 64) & (S_LEN - 1);
    vf0 = *(const bf16x8*)(Vp + (size_t)(kn + 2 * kpV) * KVD + dcV);
    vf1 = *(const bf16x8*)(Vp + (size_t)(kn + 2 * kpV + 1) * KVD + dcV);
  };
  auto vcommit = [&]() {
    const unsigned* u0 = (const unsigned*)&vf0;
    const unsigned* u1 = (const unsigned*)&vf1;
#pragma unroll
    for (int jw = 0; jw < 4; jw++) {
      unsigned lo = permb(u1[jw], u0[jw], 0x05040100u);
      unsigned hi = permb(u1[jw], u0[jw], 0x07060302u);
      *(unsigned*)(lsVt + (dcV + 2 * jw)     * ST + 2 * kpV) = lo;
      *(unsigned*)(lsVt + (dcV + 2 * jw + 1) * ST + 2 * kpV) = hi;
    }
  };

  // ---- prologue: K(0) frags + V(0) committed; V(1) prefetched ----
  kload(0);
  vprefetch(0);
  vcommit();
  __syncthreads();             // V(0) visible
  vprefetch(1);

  for (int t = 0; t < S_LEN / 64; t++) {
    // ---- S^T = K (Q')^T from registers (no LDS dependency) ----
    f32x16 s0, s1;
#pragma unroll
    for (int i = 0; i < 16; i++) { s0[i] = 0.f; s1[i] = 0.f; }
    __builtin_amdgcn_s_setprio(1);
#pragma unroll
    for (int f = 0; f < 4; f++) {
      s0 = __builtin_amdgcn_mfma_f32_32x32x16_bf16(kr[0][f], qf[f], s0, 0, 0, 0);
      s1 = __builtin_amdgcn_mfma_f32_32x32x16_bf16(kr[1][f], qf[f], s1, 0, 0, 0);
    }
    __builtin_amdgcn_s_setprio(0);
    // issue K loads for the next tile now (L2-hit latency hides under SM+PV)
    kload(t + 1);

    // ---- p = exp2(s) in place ----
#pragma unroll
    for (int i = 0; i < 16; i++) {
      s0[i] = __builtin_amdgcn_exp2f(s0[i]);
      s1[i] = __builtin_amdgcn_exp2f(s1[i]);
    }
    // ---- row-sum via packed f32 adds ----
    {
      const f32x2* p0 = (const f32x2*)&s0;
      const f32x2* p1 = (const f32x2*)&s1;
      f32x2 t0 = pk_add(p0[0], p1[0]);
      f32x2 t1 = pk_add(p0[1], p1[1]);
      f32x2 t2 = pk_add(p0[2], p1[2]);
      f32x2 t3 = pk_add(p0[3], p1[3]);
      f32x2 t4 = pk_add(p0[4], p1[4]);
      f32x2 t5 = pk_add(p0[5], p1[5]);
      f32x2 t6 = pk_add(p0[6], p1[6]);
      f32x2 t7 = pk_add(p0[7], p1[7]);
      t0 = pk_add(t0, t4); t1 = pk_add(t1, t5);
      t2 = pk_add(t2, t6); t3 = pk_add(t3, t7);
      t0 = pk_add(t0, t2); t1 = pk_add(t1, t3);
      t0 = pk_add(t0, t1);
      lloc += t0.x + t0.y;
    }
    // ---- pack to bf16 pairs ----
    int P2[2][8];
#pragma unroll
    for (int qq = 0; qq < 8; qq++) {
      P2[0][qq] = cvt_pk_bf16(s0[2 * qq], s0[2 * qq + 1]);
      P2[1][qq] = cvt_pk_bf16(s1[2 * qq], s1[2 * qq + 1]);
    }

    // ---- O += P V (V^T from LDS) ----
    __builtin_amdgcn_s_setprio(1);
#pragma unroll
    for (int tt = 0; tt < 4; tt++) {
      const int j = tt >> 1, b0 = (tt & 1) * 4;
      int w0 = P2[j][b0 + 0], w2 = P2[j][b0 + 2];
      int w1 = P2[j][b0 + 1], w3 = P2[j][b0 + 3];
      plswap(w0, w2);
      plswap(w1, w3);
      union { unsigned u[4]; bf16x8 v; } pa;
      pa.u[0] = (unsigned)w0; pa.u[1] = (unsigned)w1;
      pa.u[2] = (unsigned)w2; pa.u[3] = (unsigned)w3;
      bf16x8 bv0 = *(const bf16x8*)(lsVt + l31 * ST + tt * 16 + hl * 8);
      bf16x8 bv1 = *(const bf16x8*)(lsVt + (32 + l31) * ST + tt * 16 + hl * 8);
      o0 = __builtin_amdgcn_mfma_f32_32x32x16_bf16(pa.v, bv0, o0, 0, 0, 0);
      o1 = __builtin_amdgcn_mfma_f32_32x32x16_bf16(pa.v, bv1, o1, 0, 0, 0);
    }
    __builtin_amdgcn_s_setprio(0);
    __syncthreads();           // all waves done reading lsVt(t)
    if (t < S_LEN / 64 - 1) {
      vcommit();               // write V(t+1)
      __syncthreads();         // V(t+1) visible
      vprefetch(t + 2);
    }
  }

  const float lfull = lloc + __shfl(lloc, lane ^ 32);
  if (lane < 32) lsum[wave][lane] = lfull;
#pragma unroll
  for (int r = 0; r < 16; r++) {
    const int qrow = (r & 3) + 8 * (r >> 2) + 4 * hl;
    const float rl = 1.0f / lsum[wave][qrow];
    short* op = O + (size_t)(b * S_LEN + q0 + qrow) * HID + h * 64 + l31;
    op[0]  = f2b(o0[r] * rl);
    op[32] = f2b(o1[r] * rl);
  }
}

// ---------------------------------------------------------------------------
extern "C" void kernel_launch(void* const* d_in, const int* in_sizes, int n_in,
                              void* d_out, int out_size, void* d_ws, size_t ws_size,
                              hipStream_t stream) {
  const float* x  = (const float*)d_in[0];
  const float* wq = (const float*)d_in[1];
  const float* bq = (const float*)d_in[2];
  const float* wk = (const float*)d_in[3];
  const float* bk = (const float*)d_in[4];
  const float* wv = (const float*)d_in[5];
  const float* bv = (const float*)d_in[6];
  const float* wo = (const float*)d_in[7];
  const float* bo = (const float*)d_in[8];
  float* out = (float*)d_out;

  short* xb  = (short*)d_ws;
  short* wqb = xb  + (size_t)4096 * 2048;
  short* wkb = wqb + (size_t)2048 * 2048;
  short* wvb = wkb + (size_t)512 * 2048;
  short* wob = wvb + (size_t)512 * 2048;
  short* Qb  = wob + (size_t)2048 * 2048;
  short* Kb  = Qb  + (size_t)4096 * 2048;
  short* Vb  = Kb  + (size_t)4096 * 512;
  short* AO  = Vb  + (size_t)4096 * 512;

  dim3 blk(256);
  conv_all<<<18 * 1048576 / 1024, blk, 0, stream>>>(x, wq, wk, wv, wo, xb);

  gemm_qkv<<<dim3(3072 / 128, 4096 / 128), blk, 0, stream>>>(xb, wqb, bq, bk, bv, Qb, Kb, Vb);
  gqa_flash<<<dim3(2048 / 32, 16), blk, 0, stream>>>(Qb, Kb, Vb, AO);
  gemm_bt_bias<true><<<dim3(2048 / 128, 4096 / 128), blk, 0, stream>>>(AO, wob, bo, out, 4096, 2048, 2048);
}

// Round 10
// 309.439 us; speedup vs baseline: 1.2021x; 1.2021x over previous
//
#include <hip/hip_runtime.h>

// ---------- types ----------
typedef __attribute__((ext_vector_type(8))) short bf16x8;   // 8 bf16 = 4 VGPR
typedef __attribute__((ext_vector_type(4))) float f32x4;    // 16x16 MFMA C/D frag
typedef __attribute__((ext_vector_type(16))) float f32x16;  // 32x32 MFMA C/D frag
typedef __attribute__((ext_vector_type(2))) float f32x2;

__device__ __forceinline__ short f2b(float f) {
  union { unsigned u; float f; } c;
  c.f = f;
  unsigned r = (c.u + 0x7FFFu + ((c.u >> 16) & 1u)) >> 16;  // RNE
  return (short)r;
}

// v_cvt_pk_bf16_f32: pack two f32 -> one u32 of 2 bf16 (no builtin on gfx950)
__device__ __forceinline__ int cvt_pk_bf16(float lo, float hi) {
  int r;
  asm("v_cvt_pk_bf16_f32 %0, %1, %2" : "=v"(r) : "v"(lo), "v"(hi));
  return r;
}

// v_permlane32_swap_b32: a' = [a.lo | b.lo], b' = [a.hi | b.hi]
__device__ __forceinline__ void plswap(int& a, int& b) {
  asm("v_permlane32_swap_b32 %0, %1" : "+v"(a), "+v"(b));
}

// v_pk_add_f32: packed 2xf32 add
__device__ __forceinline__ f32x2 pk_add(f32x2 a, f32x2 b) {
  f32x2 d;
  asm("v_pk_add_f32 %0, %1, %2" : "=v"(d) : "v"(a), "v"(b));
  return d;
}

// v_perm_b32 byte shuffle
__device__ __forceinline__ unsigned permb(unsigned s0, unsigned s1, unsigned sel) {
  unsigned d;
  asm("v_perm_b32 %0, %1, %2, %3" : "=v"(d) : "v"(s0), "v"(s1), "s"(sel));
  return d;
}

// async global->LDS, 16B per lane
__device__ __forceinline__ void async16(const void* g, void* l) {
  __builtin_amdgcn_global_load_lds(
      (const __attribute__((address_space(1))) unsigned*)g,
      (__attribute__((address_space(3))) unsigned*)l, 16, 0, 0);
}

// ---------------------------------------------------------------------------
// fp32 -> bf16 conversion, all five tensors in ONE launch.
// ---------------------------------------------------------------------------
__global__ __launch_bounds__(256)
void conv_all(const float* __restrict__ x,  const float* __restrict__ wq,
              const float* __restrict__ wk, const float* __restrict__ wv,
              const float* __restrict__ wo, short* __restrict__ dst) {
  const size_t M = 1048576;
  size_t i = ((size_t)blockIdx.x * 256 + threadIdx.x) * 4;
  const float* src; size_t off;
  if (i < 8 * M)       { src = x;  off = 0; }
  else if (i < 12 * M) { src = wq; off = 8 * M; }
  else if (i < 13 * M) { src = wk; off = 12 * M; }
  else if (i < 14 * M) { src = wv; off = 13 * M; }
  else                 { src = wo; off = 14 * M; }
  float4 v = *(const float4*)(src + (i - off));
  short4 o;
  o.x = f2b(v.x); o.y = f2b(v.y); o.z = f2b(v.z); o.w = f2b(v.w);
  *(short4*)(dst + i) = o;
}

// ---------------------------------------------------------------------------
// 128x128 GEMM, BK=64, 32x32x16 MFMA (round-7 verified). XOR chunk-swizzled
// LDS; XCD-chunked block remap. C/D map: col=l31, row=(r&3)+8(r>>2)+4*hl.
// ---------------------------------------------------------------------------
template <bool F32OUT>
__global__ __launch_bounds__(256)
void gemm_bt_bias(const short* __restrict__ A, const short* __restrict__ Bw,
                  const float* __restrict__ bias, void* __restrict__ Cv,
                  int M, int N, int K) {
  __shared__ short lsA[128 * 64];
  __shared__ short lsB[128 * 64];
  const int tid  = threadIdx.x;
  const int wave = tid >> 6, lane = tid & 63;
  const int l31  = lane & 31, hl = lane >> 5;
  const int GX  = gridDim.x;
  const int nwg = GX * gridDim.y;
  const int dd  = blockIdx.x + blockIdx.y * GX;
  const int logical = (dd & 7) * (nwg >> 3) + (dd >> 3);
  const int m0 = (logical / GX) * 128, n0 = (logical % GX) * 128;
  const int wm = (wave >> 1) * 64, wn = (wave & 1) * 64;

  f32x16 acc[2][2];
#pragma unroll
  for (int i = 0; i < 2; i++)
#pragma unroll
    for (int j = 0; j < 2; j++)
#pragma unroll
      for (int r = 0; r < 16; r++) acc[i][j][r] = 0.f;

  const int R  = tid >> 3;               // 0..31
  const int cs = tid & 7;                // chunk 0..7
  const int gc = (cs ^ (R & 7)) << 3;    // pre-swizzled source column
  const short* Arow[4]; const short* Brow[4];
#pragma unroll
  for (int b = 0; b < 4; b++) {
    Arow[b] = A  + (size_t)(m0 + R + 32 * b) * K + gc;
    Brow[b] = Bw + (size_t)(n0 + R + 32 * b) * K + gc;
  }
  const int ldst = R * 64 + cs * 8;

  for (int k0 = 0; k0 < K; k0 += 64) {
#pragma unroll
    for (int b = 0; b < 4; b++) {
      async16(Arow[b] + k0, lsA + ldst + b * 32 * 64);
      async16(Brow[b] + k0, lsB + ldst + b * 32 * 64);
    }
    __syncthreads();

    bf16x8 af[2][4], bfr[2][4];
#pragma unroll
    for (int i = 0; i < 2; i++) {
      const int Rr = wm + i * 32 + l31;
#pragma unroll
      for (int kq = 0; kq < 4; kq++) {
        const int c = kq * 2 + hl;
        af[i][kq] = *(const bf16x8*)(lsA + Rr * 64 + ((c ^ (Rr & 7)) << 3));
      }
    }
#pragma unroll
    for (int j = 0; j < 2; j++) {
      const int Sr = wn + j * 32 + l31;
#pragma unroll
      for (int kq = 0; kq < 4; kq++) {
        const int c = kq * 2 + hl;
        bfr[j][kq] = *(const bf16x8*)(lsB + Sr * 64 + ((c ^ (Sr & 7)) << 3));
      }
    }
#pragma unroll
    for (int kq = 0; kq < 4; kq++)
#pragma unroll
      for (int i = 0; i < 2; i++)
#pragma unroll
        for (int j = 0; j < 2; j++)
          acc[i][j] = __builtin_amdgcn_mfma_f32_32x32x16_bf16(
              af[i][kq], bfr[j][kq], acc[i][j], 0, 0, 0);
    __syncthreads();
  }

#pragma unroll
  for (int j = 0; j < 2; j++) {
    const int col = n0 + wn + j * 32 + l31;
    const float bb = bias[col];
#pragma unroll
    for (int i = 0; i < 2; i++) {
      const int rowb = m0 + wm + i * 32;
#pragma unroll
      for (int r = 0; r < 16; r++) {
        const int row = rowb + (r & 3) + 8 * (r >> 2) + 4 * hl;
        const float val = acc[i][j][r] + bb;
        if (F32OUT)
          ((float*)Cv)[(size_t)row * N + col] = val;
        else
          ((short*)Cv)[(size_t)row * N + col] = f2b(val);
      }
    }
  }
}

// ---------------------------------------------------------------------------
// Fused QKV GEMM, same 32x32x16 structure. Q pre-scaled by 0.125*log2(e).
// ---------------------------------------------------------------------------
__global__ __launch_bounds__(256)
void gemm_qkv(const short* __restrict__ A, const short* __restrict__ Bw,
              const float* __restrict__ bq, const float* __restrict__ bk,
              const float* __restrict__ bv,
              short* __restrict__ Qo, short* __restrict__ Ko, short* __restrict__ Vo) {
  const int K = 2048;
  __shared__ short lsA[128 * 64];
  __shared__ short lsB[128 * 64];
  const int tid  = threadIdx.x;
  const int wave = tid >> 6, lane = tid & 63;
  const int l31  = lane & 31, hl = lane >> 5;
  const int GX  = gridDim.x;
  const int nwg = GX * gridDim.y;
  const int dd  = blockIdx.x + blockIdx.y * GX;
  const int logical = (dd & 7) * (nwg >> 3) + (dd >> 3);
  const int m0 = (logical / GX) * 128, n0 = (logical % GX) * 128;
  const int wm = (wave >> 1) * 64, wn = (wave & 1) * 64;

  f32x16 acc[2][2];
#pragma unroll
  for (int i = 0; i < 2; i++)
#pragma unroll
    for (int j = 0; j < 2; j++)
#pragma unroll
      for (int r = 0; r < 16; r++) acc[i][j][r] = 0.f;

  const int R  = tid >> 3;
  const int cs = tid & 7;
  const int gc = (cs ^ (R & 7)) << 3;
  const short* Arow[4]; const short* Brow[4];
#pragma unroll
  for (int b = 0; b < 4; b++) {
    Arow[b] = A  + (size_t)(m0 + R + 32 * b) * K + gc;
    Brow[b] = Bw + (size_t)(n0 + R + 32 * b) * K + gc;
  }
  const int ldst = R * 64 + cs * 8;

  for (int k0 = 0; k0 < K; k0 += 64) {
#pragma unroll
    for (int b = 0; b < 4; b++) {
      async16(Arow[b] + k0, lsA + ldst + b * 32 * 64);
      async16(Brow[b] + k0, lsB + ldst + b * 32 * 64);
    }
    __syncthreads();

    bf16x8 af[2][4], bfr[2][4];
#pragma unroll
    for (int i = 0; i < 2; i++) {
      const int Rr = wm + i * 32 + l31;
#pragma unroll
      for (int kq = 0; kq < 4; kq++) {
        const int c = kq * 2 + hl;
        af[i][kq] = *(const bf16x8*)(lsA + Rr * 64 + ((c ^ (Rr & 7)) << 3));
      }
    }
#pragma unroll
    for (int j = 0; j < 2; j++) {
      const int Sr = wn + j * 32 + l31;
#pragma unroll
      for (int kq = 0; kq < 4; kq++) {
        const int c = kq * 2 + hl;
        bfr[j][kq] = *(const bf16x8*)(lsB + Sr * 64 + ((c ^ (Sr & 7)) << 3));
      }
    }
#pragma unroll
    for (int kq = 0; kq < 4; kq++)
#pragma unroll
      for (int i = 0; i < 2; i++)
#pragma unroll
        for (int j = 0; j < 2; j++)
          acc[i][j] = __builtin_amdgcn_mfma_f32_32x32x16_bf16(
              af[i][kq], bfr[j][kq], acc[i][j], 0, 0, 0);
    __syncthreads();
  }

  short* base; int stride, coff; const float* bias;
  if (n0 < 2048)      { base = Qo; stride = 2048; bias = bq; coff = 0; }
  else if (n0 < 2560) { base = Ko; stride = 512;  bias = bk; coff = 2048; }
  else                { base = Vo; stride = 512;  bias = bv; coff = 2560; }
  const float qs = (n0 < 2048) ? 0.18033688011112043f : 1.0f;  // 0.125*log2(e)

#pragma unroll
  for (int j = 0; j < 2; j++) {
    const int lc = n0 + wn + j * 32 + l31 - coff;
    const float bb = bias[lc];
#pragma unroll
    for (int i = 0; i < 2; i++) {
      const int rowb = m0 + wm + i * 32;
#pragma unroll
      for (int r = 0; r < 16; r++) {
        const int row = rowb + (r & 3) + 8 * (r >> 2) + 4 * hl;
        base[(size_t)row * stride + lc] = f2b((acc[i][j][r] + bb) * qs);
      }
    }
  }
}

// ---------------------------------------------------------------------------
// Flash GQA v5 (verified 101.3-102 us): 32x32x16 swapped QK^T, in-register
// softmax (exp2, pk_add tree, cvt_pk, permlane32_swap), v_perm V^T pack.
// LDS 18.9 KiB, 0 bank conflicts. K-in-LDS is REQUIRED (round-9: K-from-
// global = address-divergent frag loads, -60%). Only change vs round 7:
// loop-end barrier is a raw s_barrier (skips __syncthreads' implicit
// vmcnt(0) drain of the in-flight K/V prefetch). First barrier keeps
// __syncthreads semantics (ds_write visibility for commits).
// ---------------------------------------------------------------------------
#define S_LEN 2048
#define HID   2048
#define KVD   512
#define ST    72

__global__ __launch_bounds__(256)
void gqa_flash(const short* __restrict__ Q, const short* __restrict__ Kb,
               const short* __restrict__ Vb, short* __restrict__ O) {
  __shared__ __align__(16) short lsK[64 * ST];    // [key][d]
  __shared__ __align__(16) short lsVt[64 * ST];   // [d][key]
  __shared__ float lsum[4][32];

  const int tid  = threadIdx.x;
  const int wave = tid >> 6, lane = tid & 63;
  const int l31  = lane & 31, hl = lane >> 5;

  const int d  = blockIdx.x + (blockIdx.y << 6);
  const int by = ((d & 7) << 1) | (d >> 9);
  const int qb = (d >> 3) & 63;
  const int b = by >> 3, kvh = by & 7;
  const int h = kvh * 4 + wave;
  const int q0 = qb * 32;

  const short* Qrow = Q + (size_t)(b * S_LEN + q0 + l31) * HID + h * 64 + hl * 8;
  bf16x8 qf[4];
#pragma unroll
  for (int f = 0; f < 4; f++) qf[f] = *(const bf16x8*)(Qrow + f * 16);

  f32x16 o0, o1;
#pragma unroll
  for (int i = 0; i < 16; i++) { o0[i] = 0.f; o1[i] = 0.f; }
  float lloc = 0.f;

  const short* Kp = Kb + (size_t)b * S_LEN * KVD + kvh * 64;
  const short* Vp = Vb + (size_t)b * S_LEN * KVD + kvh * 64;

  const int keyA = tid >> 3, chK = (tid & 7) * 8;
  const int kpV = tid & 31, dcV = (tid >> 5) * 8;

  bf16x8 kf0 = *(const bf16x8*)(Kp + (size_t)keyA * KVD + chK);
  bf16x8 kf1 = *(const bf16x8*)(Kp + (size_t)(keyA + 32) * KVD + chK);
  bf16x8 vf0 = *(const bf16x8*)(Vp + (size_t)(2 * kpV) * KVD + dcV);
  bf16x8 vf1 = *(const bf16x8*)(Vp + (size_t)(2 * kpV + 1) * KVD + dcV);

  for (int k0 = 0; k0 < S_LEN; k0 += 64) {
    // ---- commit prefetched K + V^T (v_perm byte-interleave) ----
    *(bf16x8*)(lsK + keyA * ST + chK) = kf0;
    *(bf16x8*)(lsK + (keyA + 32) * ST + chK) = kf1;
    {
      const unsigned* u0 = (const unsigned*)&vf0;
      const unsigned* u1 = (const unsigned*)&vf1;
#pragma unroll
      for (int jw = 0; jw < 4; jw++) {
        unsigned lo = permb(u1[jw], u0[jw], 0x05040100u);
        unsigned hi = permb(u1[jw], u0[jw], 0x07060302u);
        *(unsigned*)(lsVt + (dcV + 2 * jw)     * ST + 2 * kpV) = lo;
        *(unsigned*)(lsVt + (dcV + 2 * jw + 1) * ST + 2 * kpV) = hi;
      }
    }
    __syncthreads();   // ds_write visibility for all waves (keep full sync)

    // ---- prefetch next tile ----
    const int kn = (k0 + 64) & (S_LEN - 1);
    kf0 = *(const bf16x8*)(Kp + (size_t)(kn + keyA) * KVD + chK);
    kf1 = *(const bf16x8*)(Kp + (size_t)(kn + keyA + 32) * KVD + chK);
    vf0 = *(const bf16x8*)(Vp + (size_t)(kn + 2 * kpV) * KVD + dcV);
    vf1 = *(const bf16x8*)(Vp + (size_t)(kn + 2 * kpV + 1) * KVD + dcV);

    // ---- S^T = K (Q')^T ----
    f32x16 s0, s1;
#pragma unroll
    for (int i = 0; i < 16; i++) { s0[i] = 0.f; s1[i] = 0.f; }
    __builtin_amdgcn_s_setprio(1);
#pragma unroll
    for (int f = 0; f < 4; f++) {
      bf16x8 ka = *(const bf16x8*)(lsK + l31 * ST + f * 16 + hl * 8);
      bf16x8 kb = *(const bf16x8*)(lsK + (32 + l31) * ST + f * 16 + hl * 8);
      s0 = __builtin_amdgcn_mfma_f32_32x32x16_bf16(ka, qf[f], s0, 0, 0, 0);
      s1 = __builtin_amdgcn_mfma_f32_32x32x16_bf16(kb, qf[f], s1, 0, 0, 0);
    }
    __builtin_amdgcn_s_setprio(0);

    // ---- p = exp2(s) in place ----
#pragma unroll
    for (int i = 0; i < 16; i++) {
      s0[i] = __builtin_amdgcn_exp2f(s0[i]);
      s1[i] = __builtin_amdgcn_exp2f(s1[i]);
    }
    // ---- row-sum via packed f32 adds ----
    {
      const f32x2* p0 = (const f32x2*)&s0;
      const f32x2* p1 = (const f32x2*)&s1;
      f32x2 t0 = pk_add(p0[0], p1[0]);
      f32x2 t1 = pk_add(p0[1], p1[1]);
      f32x2 t2 = pk_add(p0[2], p1[2]);
      f32x2 t3 = pk_add(p0[3], p1[3]);
      f32x2 t4 = pk_add(p0[4], p1[4]);
      f32x2 t5 = pk_add(p0[5], p1[5]);
      f32x2 t6 = pk_add(p0[6], p1[6]);
      f32x2 t7 = pk_add(p0[7], p1[7]);
      t0 = pk_add(t0, t4); t1 = pk_add(t1, t5);
      t2 = pk_add(t2, t6); t3 = pk_add(t3, t7);
      t0 = pk_add(t0, t2); t1 = pk_add(t1, t3);
      t0 = pk_add(t0, t1);
      lloc += t0.x + t0.y;
    }
    // ---- pack to bf16 pairs ----
    int P2[2][8];
#pragma unroll
    for (int qq = 0; qq < 8; qq++) {
      P2[0][qq] = cvt_pk_bf16(s0[2 * qq], s0[2 * qq + 1]);
      P2[1][qq] = cvt_pk_bf16(s1[2 * qq], s1[2 * qq + 1]);
    }

    // ---- O += P V ----
    __builtin_amdgcn_s_setprio(1);
#pragma unroll
    for (int t = 0; t < 4; t++) {
      const int j = t >> 1, b0 = (t & 1) * 4;
      int w0 = P2[j][b0 + 0], w2 = P2[j][b0 + 2];
      int w1 = P2[j][b0 + 1], w3 = P2[j][b0 + 3];
      plswap(w0, w2);
      plswap(w1, w3);
      union { unsigned u[4]; bf16x8 v; } pa;
      pa.u[0] = (unsigned)w0; pa.u[1] = (unsigned)w1;
      pa.u[2] = (unsigned)w2; pa.u[3] = (unsigned)w3;
      bf16x8 bv0 = *(const bf16x8*)(lsVt + l31 * ST + t * 16 + hl * 8);
      bf16x8 bv1 = *(const bf16x8*)(lsVt + (32 + l31) * ST + t * 16 + hl * 8);
      o0 = __builtin_amdgcn_mfma_f32_32x32x16_bf16(pa.v, bv0, o0, 0, 0, 0);
      o1 = __builtin_amdgcn_mfma_f32_32x32x16_bf16(pa.v, bv1, o1, 0, 0, 0);
    }
    __builtin_amdgcn_s_setprio(0);
    // loop-end barrier: raw s_barrier (no vmcnt(0) drain of the prefetch).
    // All lsK/lsVt reads are consumed by MFMAs above (lgkm drained by deps);
    // next iteration's ds_writes stay after the barrier via sched_barrier.
    __builtin_amdgcn_sched_barrier(0);
    __builtin_amdgcn_s_barrier();
    __builtin_amdgcn_sched_barrier(0);
  }

  const float lfull = lloc + __shfl(lloc, lane ^ 32);
  if (lane < 32) lsum[wave][lane] = lfull;
#pragma unroll
  for (int r = 0; r < 16; r++) {
    const int qrow = (r & 3) + 8 * (r >> 2) + 4 * hl;
    const float rl = 1.0f / lsum[wave][qrow];
    short* op = O + (size_t)(b * S_LEN + q0 + qrow) * HID + h * 64 + l31;
    op[0]  = f2b(o0[r] * rl);
    op[32] = f2b(o1[r] * rl);
  }
}

// ---------------------------------------------------------------------------
extern "C" void kernel_launch(void* const* d_in, const int* in_sizes, int n_in,
                              void* d_out, int out_size, void* d_ws, size_t ws_size,
                              hipStream_t stream) {
  const float* x  = (const float*)d_in[0];
  const float* wq = (const float*)d_in[1];
  const float* bq = (const float*)d_in[2];
  const float* wk = (const float*)d_in[3];
  const float* bk = (const float*)d_in[4];
  const float* wv = (const float*)d_in[5];
  const float* bv = (const float*)d_in[6];
  const float* wo = (const float*)d_in[7];
  const float* bo = (const float*)d_in[8];
  float* out = (float*)d_out;

  short* xb  = (short*)d_ws;
  short* wqb = xb  + (size_t)4096 * 2048;
  short* wkb = wqb + (size_t)2048 * 2048;
  short* wvb = wkb + (size_t)512 * 2048;
  short* wob = wvb + (size_t)512 * 2048;
  short* Qb  = wob + (size_t)2048 * 2048;
  short* Kb  = Qb  + (size_t)4096 * 2048;
  short* Vb  = Kb  + (size_t)4096 * 512;
  short* AO  = Vb  + (size_t)4096 * 512;

  dim3 blk(256);
  conv_all<<<18 * 1048576 / 1024, blk, 0, stream>>>(x, wq, wk, wv, wo, xb);

  gemm_qkv<<<dim3(3072 / 128, 4096 / 128), blk, 0, stream>>>(xb, wqb, bq, bk, bv, Qb, Kb, Vb);
  gqa_flash<<<dim3(2048 / 32, 16), blk, 0, stream>>>(Qb, Kb, Vb, AO);
  gemm_bt_bias<true><<<dim3(2048 / 128, 4096 / 128), blk, 0, stream>>>(AO, wob, bo, out, 4096, 2048, 2048);
}